// Round 3
// baseline (602.367 us; speedup 1.0000x reference)
//
#include <hip/hip_runtime.h>

#define NB 8
#define NN 65536
#define NC 128

typedef float f32x4 __attribute__((ext_vector_type(4)));
typedef short s16x8 __attribute__((ext_vector_type(8)));

// ---- workspace layout (float offsets unless noted) ----
#define WS_G     0                    // NB*16384 floats (final G)
#define WS_XS    (NB*16384)           // NB*128 (atomic fp32 xsum)
#define WS_WDEN  (WS_XS + NB*128)     // NB*128
#define WS_BOUT  (WS_WDEN + NB*128)   // NB*128
#define WS_BDEN  (WS_BOUT + NB*128)   // NB
#define WS_WOUTF_BYTE 536640          // byte offset, bf16 NB*16384 ushorts (frag-order Wout)
#define WS_PART_FLOAT 262144          // byte 1048576: 256 partial G's (16 MB)
#define WS_NEED (1048576u + 256u*16384u*4u)

static __device__ __forceinline__ unsigned short f2bf(float f) {
  union { float f; unsigned u; } c; c.f = f;
  unsigned u = c.u;
  return (unsigned short)((u + 0x7fffu + ((u >> 16) & 1u)) >> 16);  // RNE
}
static __device__ __forceinline__ unsigned pack2(float lo, float hi) {
  return (unsigned)f2bf(lo) | ((unsigned)f2bf(hi) << 16);
}

// ============ kernel A: per-batch Gram G = x^T x (bf16 MFMA, fp32 accum) + xsum ============
// grid 256 (32 blocks/batch, 2048 rows each), block 512 (8 waves; wave w owns i-tile w)
__global__ __launch_bounds__(512) void gram_k(const float* __restrict__ x,
                                              float* __restrict__ ws, int use_part) {
  const int blk = blockIdx.x;
  const int b = blk >> 5, slot = blk & 31;
  const float* xb = x + ((size_t)b * NN + (size_t)slot * 2048) * NC;
  const int tid = threadIdx.x;
  const int lane = tid & 63, w = tid >> 6;
  const int p = tid & 15;        // row-pair within 32-row chunk
  const int q = tid >> 4;        // col-quad 0..31
  const int m = lane & 15, g = lane >> 4;

  __shared__ unsigned xT[128 * 20];      // [col][pair] u32=2xbf16, pad 20 (16B-aligned rows)
  __shared__ float xpart[16][128];

  f32x4 acc[8];
#pragma unroll
  for (int jt = 0; jt < 8; jt++) acc[jt] = (f32x4)(0.f);
  float xs[4] = {0.f, 0.f, 0.f, 0.f};

  f32x4 cur0 = *(const f32x4*)(xb + (2 * p) * NC + 4 * q);
  f32x4 cur1 = *(const f32x4*)(xb + (2 * p + 1) * NC + 4 * q);

  for (int ch = 0; ch < 64; ++ch) {
    f32x4 nxt0, nxt1;
    if (ch < 63) {  // prefetch next chunk (latency hidden under this chunk's phases)
      const float* nb = xb + (size_t)((ch + 1) * 32 + 2 * p) * NC + 4 * q;
      nxt0 = *(const f32x4*)nb;
      nxt1 = *(const f32x4*)(nb + NC);
    } else { nxt0 = cur0; nxt1 = cur1; }
    __syncthreads();  // previous chunk's frag reads done
#pragma unroll
    for (int i = 0; i < 4; i++) {
      xs[i] += cur0[i] + cur1[i];
      xT[(4 * q + i) * 20 + p] = pack2(cur0[i], cur1[i]);  // lo=row2p, hi=row2p+1
    }
    __syncthreads();
    const int fb = m * 20 + 4 * g;
    s16x8 fi = *(const s16x8*)&xT[320 * w + fb];
#pragma unroll
    for (int jt = 0; jt < 8; jt++) {
      s16x8 fj = *(const s16x8*)&xT[320 * jt + fb];
      acc[jt] = __builtin_amdgcn_mfma_f32_16x16x32_bf16(fi, fj, acc[jt], 0, 0, 0);
    }
    cur0 = nxt0; cur1 = nxt1;
  }

  // xsum: block reduce then atomic (only 256*128 atomics total)
#pragma unroll
  for (int i = 0; i < 4; i++) xpart[p][4 * q + i] = xs[i];
  __syncthreads();
  if (tid < 128) {
    float s = 0.f;
#pragma unroll
    for (int pp = 0; pp < 16; pp++) s += xpart[pp][tid];
    atomicAdd(&ws[WS_XS + b * 128 + tid], s);
  }

  float* dst = use_part ? (ws + WS_PART_FLOAT + (size_t)blk * 16384)
                        : (ws + (size_t)b * 16384);
#pragma unroll
  for (int jt = 0; jt < 8; jt++)
#pragma unroll
    for (int r = 0; r < 4; r++) {
      int idx = (16 * w + 4 * g + r) * 128 + 16 * jt + m;  // C/D: row=(l>>4)*4+r, col=l&15
      if (use_part) dst[idx] = acc[jt][r];
      else atomicAdd(&dst[idx], acc[jt][r]);
    }
}

// ============ reduce partial G's ============
__global__ __launch_bounds__(256) void reduce_k(float* __restrict__ ws) {
  int o = blockIdx.x * 256 + threadIdx.x;  // 131072 outputs
  int b = o >> 14, e = o & 16383;
  const float* p = ws + WS_PART_FLOAT + (size_t)(b * 32) * 16384 + e;
  float s = 0.f;
#pragma unroll 4
  for (int k = 0; k < 32; k++) s += p[(size_t)k * 16384];
  ws[(size_t)b * 16384 + e] = s;
}

// ============ kernel B: weight chain ============
// Wout = [ (Wq^T Wk) G Wv^T + (Wq^T bk) s_v^T + (Wq^T s_k) bv^T + N (Wq^T bk) bv^T ] / N
// wden = Wq^T Ksum, Ksum = Wk xsum + N bk; bout = bq^T KV; bden = bq.Ksum
// grid 64 (batch b = blk>>3, row-slice s = blk&7), block 256
__global__ __launch_bounds__(256) void prep_k(const float* __restrict__ Wq, const float* __restrict__ bq,
                                              const float* __restrict__ Wk, const float* __restrict__ bk,
                                              const float* __restrict__ Wv, const float* __restrict__ bv,
                                              float* __restrict__ ws, unsigned short* __restrict__ woutf) {
  const int b = blockIdx.x >> 3, s = blockIdx.x & 7;
  const float* G = ws + (size_t)b * 16384;  // L2-resident
  const int tid = threadIdx.x;
  __shared__ float xsl[128], skl[128], svl[128], tl[128], Ksl[128], gtl[128];
  __shared__ float u1l[16], u2l[16], scal[2];
  __shared__ float M1s[2048], M2s[2048];

  if (tid < 128) xsl[tid] = ws[WS_XS + b * 128 + tid];
  __syncthreads();
  if (tid < 128) {
    float a = 0.f; const float* wr = Wk + tid * 128;
    for (int i = 0; i < 128; i++) a += wr[i] * xsl[i];
    skl[tid] = a; Ksl[tid] = a + 65536.0f * bk[tid];
  } else {
    int d = tid & 127; float a = 0.f; const float* wr = Wv + d * 128;
    for (int i = 0; i < 128; i++) a += wr[i] * xsl[i];
    svl[d] = a;
  }
  __syncthreads();
  if (tid < 128) {
    float a = 0.f;
    for (int d = 0; d < 128; d++) a += Wk[d * 128 + tid] * bq[d];
    tl[tid] = a;                                   // t = Wk^T bq
  } else if (tid < 144) {
    int i = tid - 128; float a = 0.f, c2 = 0.f;
    for (int d = 0; d < 128; d++) { float wq = Wq[d * 128 + s * 16 + i]; a += wq * bk[d]; c2 += wq * skl[d]; }
    u1l[i] = a; u2l[i] = c2;
  } else if (tid == 144) {
    float a = 0.f, c2 = 0.f;
    for (int d = 0; d < 128; d++) { a += bq[d] * bk[d]; c2 += bq[d] * skl[d]; }
    scal[0] = a; scal[1] = c2;
  }
  __syncthreads();
  {  // M1 slice = (Wq^T Wk)[16s+i][k]
    int i = tid >> 4, k0 = (tid & 15) * 8;
    float av[8] = {};
    for (int d = 0; d < 128; d++) {
      float wq = Wq[d * 128 + s * 16 + i];
      const float* wk = Wk + d * 128 + k0;
#pragma unroll
      for (int u = 0; u < 8; u++) av[u] += wq * wk[u];
    }
#pragma unroll
    for (int u = 0; u < 8; u++) M1s[i * 128 + k0 + u] = av[u];
  }
  __syncthreads();
  {  // M2 slice = M1 G
    int i = tid >> 4, j0 = (tid & 15) * 8;
    float av[8] = {};
    for (int k = 0; k < 128; k++) {
      float m1 = M1s[i * 128 + k];
      const float* gr = G + k * 128 + j0;
#pragma unroll
      for (int u = 0; u < 8; u++) av[u] += m1 * gr[u];
    }
#pragma unroll
    for (int u = 0; u < 8; u++) M2s[i * 128 + j0 + u] = av[u];
  }
  if (tid < 128) {  // gt = G t (G symmetric)
    float a = 0.f;
    for (int i = 0; i < 128; i++) a += G[i * 128 + tid] * tl[i];
    gtl[tid] = a;
  }
  __syncthreads();
  {  // Wout slice, written bf16 in MFMA-fragment order
    int c = tid & 127, ih = tid >> 7;
    float av[8] = {};
    for (int j = 0; j < 128; j++) {
      float wv = Wv[c * 128 + j];
#pragma unroll
      for (int u = 0; u < 8; u++) av[u] += wv * M2s[(ih * 8 + u) * 128 + j];
    }
    const float invN = 1.0f / 65536.0f;
#pragma unroll
    for (int u = 0; u < 8; u++) {
      int i = ih * 8 + u, ig = s * 16 + i;
      float val = (av[u] + u1l[i] * svl[c] + u2l[i] * bv[c]) * invN + u1l[i] * bv[c];
      int ks = ig >> 5, gg = (ig >> 3) & 3, uu = ig & 7, nt = c >> 4, mm = c & 15;
      woutf[(size_t)b * 16384 + (size_t)(((ks * 8 + nt) * 64) + gg * 16 + mm) * 8 + uu] = f2bf(val);
    }
  }
  if (tid < 16) {
    float a = 0.f;
    for (int d = 0; d < 128; d++) a += Wq[d * 128 + s * 16 + tid] * Ksl[d];
    ws[WS_WDEN + b * 128 + s * 16 + tid] = a;
  } else if (tid < 32) {
    int c = s * 16 + (tid - 16); float a = 0.f;
    for (int j = 0; j < 128; j++) a += Wv[c * 128 + j] * gtl[j];
    float val = (a + scal[0] * svl[c] + scal[1] * bv[c]) * (1.0f / 65536.0f) + scal[0] * bv[c];
    ws[WS_BOUT + b * 128 + c] = val;
  } else if (tid == 32 && s == 0) {
    float a = 0.f;
    for (int d = 0; d < 128; d++) a += bq[d] * Ksl[d];
    ws[WS_BDEN + b] = a;
  }
}

// ============ kernel C: out = LN( (x·Wout + bout)·rs/|x·wden + bden| + x ) ============
// grid 1024 (128 blocks/batch, 512 rows each), block 256 (4 waves × 8 tiles of 16 rows)
__global__ __launch_bounds__(256) void out_k(const float* __restrict__ x,
                                             const unsigned short* __restrict__ woutf,
                                             const float* __restrict__ ws,
                                             const float* __restrict__ lnw, const float* __restrict__ lnb,
                                             const float* __restrict__ rsp, float* __restrict__ out) {
  const int blk = blockIdx.x;
  const int b = blk >> 7, sl = blk & 127;
  const size_t rowbase = (size_t)b * NN + (size_t)sl * 512;
  const int tid = threadIdx.x;
  const int lane = tid & 63, w = tid >> 6;
  const int m = lane & 15, g = lane >> 4;

  __shared__ f32x4 wldsv[2048];  // 32 KB: Wout frags for this batch
  {
    const f32x4* src = (const f32x4*)(woutf + (size_t)b * 16384);
#pragma unroll
    for (int it = 0; it < 8; ++it) wldsv[it * 256 + tid] = src[it * 256 + tid];
  }
  const unsigned short* wl = (const unsigned short*)wldsv;

  float wdenv[8], boutv[8], lnwv[8], lnbv[8];
#pragma unroll
  for (int nt = 0; nt < 8; nt++) {
    int c = nt * 16 + m;
    wdenv[nt] = ws[WS_WDEN + b * 128 + c];
    boutv[nt] = ws[WS_BOUT + b * 128 + c];
    lnwv[nt] = lnw[c]; lnbv[nt] = lnb[c];
  }
  const double bdenb = (double)ws[WS_BDEN + b];
  const float rs = rsp[0];
  __syncthreads();

  for (int t = 0; t < 8; ++t) {
    const size_t r0t = rowbase + (size_t)w * 128 + (size_t)t * 16;
    const float* xt = x + r0t * NC;
    f32x4 av[8];
#pragma unroll
    for (int ks = 0; ks < 4; ks++) {  // A-frag: row=m, k=ks*32+8g+u
      av[2 * ks]     = *(const f32x4*)(xt + m * NC + ks * 32 + 8 * g);
      av[2 * ks + 1] = *(const f32x4*)(xt + m * NC + ks * 32 + 8 * g + 4);
    }
    float xv[8][4];
#pragma unroll
    for (int nt = 0; nt < 8; nt++)
#pragma unroll
      for (int r = 0; r < 4; r++)
        xv[nt][r] = xt[(4 * g + r) * NC + nt * 16 + m];  // C/D layout (L1/L2 hit)

    f32x4 acc[8];
#pragma unroll
    for (int nt = 0; nt < 8; nt++) acc[nt] = (f32x4)(0.f);
#pragma unroll
    for (int ks = 0; ks < 4; ks++) {
      union { s16x8 v; unsigned short u16[8]; } af;
#pragma unroll
      for (int u = 0; u < 4; u++) { af.u16[u] = f2bf(av[2 * ks][u]); af.u16[4 + u] = f2bf(av[2 * ks + 1][u]); }
#pragma unroll
      for (int nt = 0; nt < 8; nt++) {
        s16x8 bf = *(const s16x8*)&wl[(size_t)(((ks * 8 + nt) * 64) + lane) * 8];
        acc[nt] = __builtin_amdgcn_mfma_f32_16x16x32_bf16(af.v, bf, acc[nt], 0, 0, 0);
      }
    }
    float sc[4];
#pragma unroll
    for (int r = 0; r < 4; r++) {  // denom in fp64 (np-f64-ref safety on near-zero rows)
      double dp = 0.0;
#pragma unroll
      for (int nt = 0; nt < 8; nt++) dp += (double)xv[nt][r] * (double)wdenv[nt];
      dp += __shfl_xor(dp, 1, 64); dp += __shfl_xor(dp, 2, 64);
      dp += __shfl_xor(dp, 4, 64); dp += __shfl_xor(dp, 8, 64);
      double dn = fabs(dp + bdenb); dn = dn > 1e-6 ? dn : 1e-6;
      sc[r] = (float)((double)rs / dn);
    }
    float s1[4] = {0.f, 0.f, 0.f, 0.f}, s2[4] = {0.f, 0.f, 0.f, 0.f};
#pragma unroll
    for (int nt = 0; nt < 8; nt++)
#pragma unroll
      for (int r = 0; r < 4; r++) {
        float y = (acc[nt][r] + boutv[nt]) * sc[r] + xv[nt][r];
        xv[nt][r] = y; s1[r] += y; s2[r] += y * y;
      }
#pragma unroll
    for (int r = 0; r < 4; r++) {
      s1[r] += __shfl_xor(s1[r], 1, 64); s1[r] += __shfl_xor(s1[r], 2, 64);
      s1[r] += __shfl_xor(s1[r], 4, 64); s1[r] += __shfl_xor(s1[r], 8, 64);
      s2[r] += __shfl_xor(s2[r], 1, 64); s2[r] += __shfl_xor(s2[r], 2, 64);
      s2[r] += __shfl_xor(s2[r], 4, 64); s2[r] += __shfl_xor(s2[r], 8, 64);
      float mean = s1[r] * (1.f / 128.f);
      float var = s2[r] * (1.f / 128.f) - mean * mean;
      s1[r] = mean; s2[r] = rsqrtf(var + 1e-5f);
    }
    float* ot = out + r0t * NC;
#pragma unroll
    for (int nt = 0; nt < 8; nt++)
#pragma unroll
      for (int r = 0; r < 4; r++)
        ot[(4 * g + r) * NC + nt * 16 + m] = (xv[nt][r] - s1[r]) * s2[r] * lnwv[nt] + lnbv[nt];
  }
}

extern "C" void kernel_launch(void* const* d_in, const int* in_sizes, int n_in,
                              void* d_out, int out_size, void* d_ws, size_t ws_size,
                              hipStream_t stream) {
  const float* x   = (const float*)d_in[0];
  const float* Wq  = (const float*)d_in[1];
  const float* bq  = (const float*)d_in[2];
  const float* Wk  = (const float*)d_in[3];
  const float* bk  = (const float*)d_in[4];
  const float* Wv  = (const float*)d_in[5];
  const float* bv  = (const float*)d_in[6];
  const float* lnw = (const float*)d_in[7];
  const float* lnb = (const float*)d_in[8];
  const float* rs  = (const float*)d_in[9];
  float* out = (float*)d_out;
  float* ws = (float*)d_ws;
  unsigned short* woutf = (unsigned short*)((char*)d_ws + WS_WOUTF_BYTE);
  int use_part = (ws_size >= (size_t)WS_NEED) ? 1 : 0;
  if (use_part) {
    hipMemsetAsync((char*)d_ws + (size_t)WS_XS * 4, 0, NB * 128 * 4, stream);  // xsum only
  } else {
    hipMemsetAsync(d_ws, 0, (size_t)(WS_XS + NB * 128) * 4, stream);  // G + xsum (atomic mode)
  }
  gram_k<<<256, 512, 0, stream>>>(x, ws, use_part);
  if (use_part) reduce_k<<<512, 256, 0, stream>>>(ws);
  prep_k<<<64, 256, 0, stream>>>(Wq, bq, Wk, bk, Wv, bv, ws, woutf);
  out_k<<<1024, 256, 0, stream>>>(x, woutf, ws, lnw, lnb, rs, out);
}